// Round 4
// baseline (696.282 us; speedup 1.0000x reference)
//
#include <hip/hip_runtime.h>
#include <math.h>

// Problem constants: B=8, L=512, H=8, vd=64, M=64, S=2, hdim=512.
// All f32. Pipeline:
//  gemm_nt<0>: qkv = x @ W_qkv^T -> qs (ARD-scaled q) + vg, fused qn row-norms
//  k2_kbeta  : k_beta (ARD-scaled) + norms
//  k3_chol   : K_kk, KL vKv term, cholesky, explicit Linv (per head)
//  ks_build  : s_local matrices + KL s2/log terms
//  k4_fused  : K_qk_beta -> v1 = Linv*K_kq, v1sq, meanA = Kqk@v_beta
//  k5_v2     : v2 = v1 @ v_gamma (+ KL per-b v2^2)
//  k6_mean1  : mean += K_qq @ v_gamma (+ KL per-b vg*mean1)
//  k10_v3sq  : v3sq[b,h,d,l] = || v1_l^T S_hd ||^2  (triangular-skip GEMM)
//  k8_samples: mean2 subtract, chol_covar, samples
//  gemm_nt<1>: out = samples @ W_O^T + b
//  kfin      : assemble KL scalar -> d_out[4194304]

#define NB 8
#define NL 512
#define NH 8
#define NVD 64
#define NM 64
#define NS 2

// ---- workspace layout (floats) ----
static const size_t OFF_QS   = 0;                       // 2097152
static const size_t OFF_VG   = OFF_QS   + 2097152;      // 2097152
static const size_t OFF_QN   = OFF_VG   + 2097152;      // 32768
static const size_t OFF_KBS  = OFF_QN   + 32768;        // 32768
static const size_t OFF_KBN  = OFF_KBS  + 32768;        // 512
static const size_t OFF_LINV = OFF_KBN  + 512;          // 32768
static const size_t OFF_V1   = OFF_LINV + 32768;        // 2097152
static const size_t OFF_V1SQ = OFF_V1   + 2097152;      // 32768
static const size_t OFF_MEAN = OFF_V1SQ + 32768;        // 2097152
static const size_t OFF_V2   = OFF_MEAN + 2097152;      // 262144
static const size_t OFF_SBUF = OFF_V2   + 262144;       // 2097152
static const size_t OFF_V3   = OFF_SBUF + 2097152;      // 2097152
static const size_t OFF_SMP  = OFF_V3   + 2097152;      // 4194304
static const size_t OFF_KL   = OFF_SMP  + 4194304;      // 32
// total ~17.2M floats = ~66 MiB

// ---------- shared helpers (blockDim.x == 256 required) ----------
// stage a 64x64 tile transposed into LDS [64][68]: dst[c][r] = src[r][c]
__device__ __forceinline__ void load_tile_t(float* dst, const float* src, int ld) {
  int t = threadIdx.x;
  int r = t >> 2;
  int c0 = (t & 3) * 16;
#pragma unroll
  for (int q = 0; q < 4; ++q) {
    float4 v = *(const float4*)(src + (size_t)r * ld + c0 + q * 4);
    int c = c0 + q * 4;
    dst[(c + 0) * 68 + r] = v.x;
    dst[(c + 1) * 68 + r] = v.y;
    dst[(c + 2) * 68 + r] = v.z;
    dst[(c + 3) * 68 + r] = v.w;
  }
}
// stage a 64x64 tile natural into LDS [64][68]
__device__ __forceinline__ void load_tile_n(float* dst, const float* src, int ld) {
  int t = threadIdx.x;
  int r = t >> 2;
  int c0 = (t & 3) * 16;
#pragma unroll
  for (int q = 0; q < 4; ++q) {
    float4 v = *(const float4*)(src + (size_t)r * ld + c0 + q * 4);
    *(float4*)(dst + r * 68 + c0 + q * 4) = v;
  }
}
// acc[i][j] += sum_k aT[k][tr+i] * bT[k][tn+j]  (both [64][68] k-major)
__device__ __forceinline__ void mma64(const float* aT, const float* bT, int tr, int tn,
                                      float acc[4][4]) {
#pragma unroll 16
  for (int k = 0; k < 64; ++k) {
    float4 av = *(const float4*)(aT + k * 68 + tr);
    float4 bv = *(const float4*)(bT + k * 68 + tn);
    float a[4] = {av.x, av.y, av.z, av.w};
    float b[4] = {bv.x, bv.y, bv.z, bv.w};
#pragma unroll
    for (int i = 0; i < 4; ++i)
#pragma unroll
      for (int j = 0; j < 4; ++j) acc[i][j] = fmaf(a[i], b[j], acc[i][j]);
  }
}
// dual-B variant: one pass over aT feeds two accumulators (saves a full
// re-read of aT from LDS; 32 FMA per 48 LDS bytes instead of 16 per 32)
__device__ __forceinline__ void mma64_dual(const float* aT, const float* b1T,
                                           const float* b2T, int tr, int tn,
                                           float acc1[4][4], float acc2[4][4]) {
#pragma unroll 8
  for (int k = 0; k < 64; ++k) {
    float4 av = *(const float4*)(aT + k * 68 + tr);
    float4 b1 = *(const float4*)(b1T + k * 68 + tn);
    float4 b2 = *(const float4*)(b2T + k * 68 + tn);
    float a[4] = {av.x, av.y, av.z, av.w};
    float p[4] = {b1.x, b1.y, b1.z, b1.w};
    float q[4] = {b2.x, b2.y, b2.z, b2.w};
#pragma unroll
    for (int i = 0; i < 4; ++i)
#pragma unroll
      for (int j = 0; j < 4; ++j) {
        acc1[i][j] = fmaf(a[i], p[j], acc1[i][j]);
        acc2[i][j] = fmaf(a[i], q[j], acc2[i][j]);
      }
  }
}

// ---------- NT GEMM: C[r][n] = sum_k A[r][k]*B[n][k], 64x64 tile ----------
// EPI 0: qkv epilogue. Block-uniform split: (n0&64)==0 -> ARD-scaled q
//        (+ fused qn row-norm reduction), else v_gamma. float4 stores.
// EPI 1: +bias -> out
template <int EPI>
__global__ __launch_bounds__(256) void gemm_nt_kernel(
    const float* __restrict__ A, const float* __restrict__ Bm, int K,
    float* __restrict__ o0, float* __restrict__ o1, const float* __restrict__ aux,
    float* __restrict__ qn) {
  __shared__ float As[16][68];
  __shared__ float Bs[16][68];
  const int t = threadIdx.x;
  const int r0 = blockIdx.x * 64;
  const int n0 = blockIdx.y * 64;
  const int lr = t >> 2;
  const int lk = (t & 3) * 4;
  const int tr = (t >> 4) * 4;
  const int tn = (t & 15) * 4;
  const float* Ap = A + (size_t)(r0 + lr) * K + lk;
  const float* Bp = Bm + (size_t)(n0 + lr) * K + lk;
  float acc[4][4] = {};
  for (int k0 = 0; k0 < K; k0 += 16) {
    float4 a4 = *(const float4*)(Ap + k0);
    float4 b4 = *(const float4*)(Bp + k0);
    As[lk + 0][lr] = a4.x; As[lk + 1][lr] = a4.y; As[lk + 2][lr] = a4.z; As[lk + 3][lr] = a4.w;
    Bs[lk + 0][lr] = b4.x; Bs[lk + 1][lr] = b4.y; Bs[lk + 2][lr] = b4.z; Bs[lk + 3][lr] = b4.w;
    __syncthreads();
#pragma unroll
    for (int k = 0; k < 16; ++k) {
      float4 av = *(const float4*)&As[k][tr];
      float4 bv = *(const float4*)&Bs[k][tn];
      float a[4] = {av.x, av.y, av.z, av.w};
      float b[4] = {bv.x, bv.y, bv.z, bv.w};
#pragma unroll
      for (int i = 0; i < 4; ++i)
#pragma unroll
        for (int j = 0; j < 4; ++j) acc[i][j] = fmaf(a[i], b[j], acc[i][j]);
    }
    __syncthreads();
  }
  if (EPI == 0) {
    const int h = n0 >> 7;
    const bool isq = (n0 & 64) == 0;  // block-uniform
    if (isq) {
      // q columns: c = tn+j (n0 = h*128). ARD-scale, store, fused row-norm.
      float invls[4];
#pragma unroll
      for (int j = 0; j < 4; ++j) invls[j] = __expf(-aux[h * 64 + tn + j]);
      float* red = &As[0][0];  // reuse: 16*68 = 1088 floats = 64*17 exactly
#pragma unroll
      for (int i = 0; i < 4; ++i) {
        int r = r0 + tr + i;
        int b = r >> 9, l = r & 511;
        float4 o;
        o.x = acc[i][0] * invls[0];
        o.y = acc[i][1] * invls[1];
        o.z = acc[i][2] * invls[2];
        o.w = acc[i][3] * invls[3];
        *(float4*)(o0 + (((size_t)(b * 8 + h)) * 512 + l) * 64 + tn) = o;
        red[(tr + i) * 17 + (t & 15)] = o.x * o.x + o.y * o.y + o.z * o.z + o.w * o.w;
      }
      __syncthreads();
      if (t < 64) {
        float s = 0.f;
#pragma unroll
        for (int g = 0; g < 16; ++g) s += red[t * 17 + g];
        int r = r0 + t;
        int b = r >> 9, l = r & 511;
        qn[(b * 8 + h) * 512 + l] = s;
      }
    } else {
      // v_gamma columns: c-64 = tn+j (n0 = h*128+64)
#pragma unroll
      for (int i = 0; i < 4; ++i) {
        int r = r0 + tr + i;
        int b = r >> 9, l = r & 511;
        float4 o = {acc[i][0], acc[i][1], acc[i][2], acc[i][3]};
        *(float4*)(o1 + (((size_t)(b * 8 + h)) * 512 + l) * 64 + tn) = o;
      }
    }
  } else {
#pragma unroll
    for (int i = 0; i < 4; ++i) {
      int r = r0 + tr + i;
      float4 o;
      o.x = acc[i][0] + aux[n0 + tn + 0];
      o.y = acc[i][1] + aux[n0 + tn + 1];
      o.z = acc[i][2] + aux[n0 + tn + 2];
      o.w = acc[i][3] + aux[n0 + tn + 3];
      *(float4*)(o0 + (size_t)r * 512 + n0 + tn) = o;
    }
  }
}

// ---------- k2: k_beta (ARD-scaled) + norms; one block per (h,m) ----------
__global__ __launch_bounds__(256) void k2_kbeta(const float* __restrict__ W,
                                                const float* __restrict__ ckg,
                                                const float* __restrict__ log_ls,
                                                float* __restrict__ kbs,
                                                float* __restrict__ kbn) {
  __shared__ float ck[512];
  __shared__ float kb[64];
  int h = blockIdx.x >> 6, m = blockIdx.x & 63;
  int t = threadIdx.x;
  ck[t] = ckg[m * 512 + t];
  ck[t + 256] = ckg[m * 512 + t + 256];
  __syncthreads();
  int w = t >> 6, lane = t & 63;
  for (int d = w; d < 64; d += 4) {
    const float* row = W + (size_t)(h * 64 + d) * 512;
    float p = 0.f;
    for (int k = lane; k < 512; k += 64) p = fmaf(row[k], ck[k], p);
#pragma unroll
    for (int off = 32; off > 0; off >>= 1) p += __shfl_down(p, off);
    if (lane == 0) {
      float v = p * __expf(-log_ls[h * 64 + d]);
      kbs[(size_t)h * 4096 + m * 64 + d] = v;
      kb[d] = v;
    }
  }
  __syncthreads();
  if (w == 0) {
    float v = kb[lane];
    v *= v;
#pragma unroll
    for (int off = 32; off > 0; off >>= 1) v += __shfl_down(v, off);
    if (lane == 0) kbn[h * 64 + m] = v;
  }
}

// ---------- k3: K_kk, KL vKv, cholesky, Linv (per head, 64 threads) ----------
__global__ __launch_bounds__(64) void k3_chol(const float* __restrict__ kbs,
                                              const float* __restrict__ kbn,
                                              const float* __restrict__ vind,
                                              const float* __restrict__ log_sf,
                                              float* __restrict__ linv_g,
                                              float* __restrict__ klbuf) {
  __shared__ float Am[64][65];
  __shared__ float Bm[64][65];
  __shared__ float kn[64];
  int h = blockIdx.x;
  int t = threadIdx.x;
  for (int m = 0; m < 64; ++m) Bm[m][t] = kbs[(size_t)h * 4096 + m * 64 + t];
  kn[t] = kbn[h * 64 + t];
  float lsf = log_sf[h];
  __syncthreads();
  float nh = -0.5f * kn[t] + lsf;
  for (int n = 0; n < 64; ++n) {  // thread t builds row t of K_kk
    float dt = 0.f;
#pragma unroll 8
    for (int d = 0; d < 64; ++d) dt = fmaf(Bm[t][d], Bm[n][d], dt);
    Am[t][n] = __expf(dt + nh - 0.5f * kn[n]);
  }
  __syncthreads();
  // KL vKv term (pre-jitter): load v_beta into Bm
  for (int m = 0; m < 64; ++m) Bm[m][t] = vind[(size_t)h * 4096 + m * 64 + t];
  __syncthreads();
  float s = 0.f;
  for (int m = 0; m < 64; ++m) {
    float tt = 0.f;
    for (int n = 0; n < 64; ++n) tt = fmaf(Am[m][n], Bm[n][t], tt);
    s = fmaf(Bm[m][t], tt, s);
  }
#pragma unroll
  for (int off = 32; off > 0; off >>= 1) s += __shfl_down(s, off);
  if (t == 0) atomicAdd(&klbuf[1], 0.5f * s);
  __syncthreads();
  Am[t][t] += 1e-4f;  // jitter
  __syncthreads();
  // cholesky (lower), right-looking
  for (int k = 0; k < 64; ++k) {
    if (t == k) Am[k][k] = sqrtf(Am[k][k]);
    __syncthreads();
    if (t > k) Am[t][k] /= Am[k][k];
    __syncthreads();
    if (t > k) {
      float f = Am[t][k];
      for (int j = k + 1; j <= t; ++j) Am[t][j] = fmaf(-f, Am[j][k], Am[t][j]);
    }
    __syncthreads();
  }
  // Linv: thread t computes column t by forward substitution
  for (int i = 0; i < t; ++i) Bm[i][t] = 0.f;
  Bm[t][t] = 1.f / Am[t][t];
  for (int i = t + 1; i < 64; ++i) {
    float a = 0.f;
    for (int j = t; j < i; ++j) a = fmaf(Am[i][j], Bm[j][t], a);
    Bm[i][t] = -a / Am[i][i];
  }
  __syncthreads();
  for (int m = 0; m < 64; ++m) linv_g[(size_t)h * 4096 + m * 64 + t] = Bm[m][t];
}

// ---------- ks_build: s_local dense matrices + KL s2/log partials ----------
__global__ __launch_bounds__(256) void ks_build(const float* __restrict__ ltri,
                                                const float* __restrict__ ldiag,
                                                float* __restrict__ sbuf,
                                                float* __restrict__ klbuf) {
  __shared__ float r1[256], r2[256];
  int hd = blockIdx.x;  // h*64 + d
  int t = threadIdx.x;
  float p2 = 0.f, pl = 0.f;
  for (int i = t; i < 4096; i += 256) {
    int m = i >> 6, n = i & 63;
    float v;
    if (m == n) v = __expf(ldiag[hd * 64 + m]);
    else if (m > n) v = ltri[(size_t)hd * 4096 + i];
    else v = 0.f;
    sbuf[(size_t)hd * 4096 + i] = v;
    p2 = fmaf(0.5f * v, v, p2);
  }
  if (t < 64) pl = ldiag[hd * 64 + t];
  r1[t] = p2;
  r2[t] = pl;
  __syncthreads();
  for (int sft = 128; sft > 0; sft >>= 1) {
    if (t < sft) { r1[t] += r1[t + sft]; r2[t] += r2[t + sft]; }
    __syncthreads();
  }
  if (t == 0) {
    atomicAdd(&klbuf[0], r1[0]);
    atomicAdd(&klbuf[2], r2[0]);
  }
}

// ---------- k4: fused K_qk_beta -> v1, v1sq, meanA ----------
__global__ __launch_bounds__(256) void k4_fused(
    const float* __restrict__ qs, const float* __restrict__ qn,
    const float* __restrict__ kbs, const float* __restrict__ kbn,
    const float* __restrict__ linv, const float* __restrict__ vind,
    const float* __restrict__ log_sf, float* __restrict__ v1,
    float* __restrict__ v1sq, float* __restrict__ meanbuf) {
  extern __shared__ float lds[];
  float* qsT = lds;              // [d][l], later reused as kvT [m][l]
  float* kbT = lds + 4352;       // [d][m]
  float* liT = lds + 2 * 4352;   // [j][m]
  float* vbN = lds + 3 * 4352;   // [m][d]
  float* red = lds + 4 * 4352;   // [64][17]
  __shared__ float qn_s[64], kbn_s[64];
  const int lt = blockIdx.x, bh = blockIdx.y;
  const int h = bh & 7;
  const int t = threadIdx.x;
  const int l0 = lt * 64;
  const int tr = (t >> 4) * 4, tn = (t & 15) * 4;
  load_tile_t(qsT, qs + ((size_t)bh * 512 + l0) * 64, 64);
  load_tile_t(kbT, kbs + (size_t)h * 4096, 64);
  load_tile_t(liT, linv + (size_t)h * 4096, 64);
  load_tile_n(vbN, vind + (size_t)h * 4096, 64);
  if (t < 64) {
    qn_s[t] = qn[bh * 512 + l0 + t];
    kbn_s[t] = kbn[h * 64 + t];
  }
  __syncthreads();
  float acc[4][4] = {};
  mma64(qsT, kbT, tr, tn, acc);  // qs . kbs
  const float lsf = log_sf[h];
  float arow[4], acol[4];
#pragma unroll
  for (int i = 0; i < 4; ++i) arow[i] = -0.5f * qn_s[tr + i];
#pragma unroll
  for (int j = 0; j < 4; ++j) acol[j] = -0.5f * kbn_s[tn + j] + lsf;
  float kv[4][4];
#pragma unroll
  for (int i = 0; i < 4; ++i)
#pragma unroll
    for (int j = 0; j < 4; ++j) kv[i][j] = __expf(acc[i][j] + arow[i] + acol[j]);
  __syncthreads();
#pragma unroll
  for (int i = 0; i < 4; ++i)
#pragma unroll
    for (int j = 0; j < 4; ++j) qsT[(tn + j) * 68 + (tr + i)] = kv[i][j];  // kvT[m][l]
  __syncthreads();
  float a2[4][4] = {};
  float a3[4][4] = {};
  // one pass over kvT feeds both v1 (vs Linv) and meanA (vs v_beta)
  mma64_dual(qsT, liT, vbN, tr, tn, a2, a3);
#pragma unroll
  for (int i = 0; i < 4; ++i) {
    float4 o = {a2[i][0], a2[i][1], a2[i][2], a2[i][3]};
    *(float4*)(v1 + ((size_t)bh * 512 + l0 + tr + i) * 64 + tn) = o;
    red[(tr + i) * 17 + (t & 15)] =
        a2[i][0] * a2[i][0] + a2[i][1] * a2[i][1] + a2[i][2] * a2[i][2] + a2[i][3] * a2[i][3];
    float4 o3 = {a3[i][0], a3[i][1], a3[i][2], a3[i][3]};
    *(float4*)(meanbuf + ((size_t)bh * 512 + l0 + tr + i) * 64 + tn) = o3;
  }
  __syncthreads();
  if (t < 64) {
    float s2 = 0.f;
#pragma unroll
    for (int g = 0; g < 16; ++g) s2 += red[t * 17 + g];
    v1sq[bh * 512 + l0 + t] = s2;
  }
}

// ---------- k5: v2 = v1^T-layout product with v_gamma; + KL v2^2 ----------
__global__ __launch_bounds__(256) void k5_v2(const float* __restrict__ v1,
                                             const float* __restrict__ vg,
                                             float* __restrict__ v2,
                                             float* __restrict__ klbuf) {
  __shared__ float v1t[64 * 68];
  __shared__ float vgt[64 * 68];
  __shared__ float redp[256];
  const int bh = blockIdx.x;
  const int b = bh >> 3;
  const int t = threadIdx.x;
  const int tr = (t >> 4) * 4, tn = (t & 15) * 4;
  float acc[4][4] = {};
  for (int c0 = 0; c0 < 512; c0 += 64) {
    __syncthreads();
    load_tile_n(v1t, v1 + ((size_t)bh * 512 + c0) * 64, 64);
    load_tile_n(vgt, vg + ((size_t)bh * 512 + c0) * 64, 64);
    __syncthreads();
    mma64(v1t, vgt, tr, tn, acc);  // v2[m][d] += sum_l v1[l][m] vg[l][d]
  }
  float p = 0.f;
#pragma unroll
  for (int i = 0; i < 4; ++i) {
    float4 o = {acc[i][0], acc[i][1], acc[i][2], acc[i][3]};
    *(float4*)(v2 + ((size_t)bh * 64 + tr + i) * 64 + tn) = o;
    p += acc[i][0] * acc[i][0] + acc[i][1] * acc[i][1] + acc[i][2] * acc[i][2] +
         acc[i][3] * acc[i][3];
  }
  redp[t] = p;
  __syncthreads();
  if (t < 64) {
    float s = redp[t] + redp[t + 64] + redp[t + 128] + redp[t + 192];
#pragma unroll
    for (int off = 32; off > 0; off >>= 1) s += __shfl_down(s, off);
    if (t == 0) atomicAdd(&klbuf[11 + b], s);
  }
}

// ---------- k6: mean += K_qq @ v_gamma; KL per-b vg*mean1 ----------
__global__ __launch_bounds__(256) void k6_mean1(const float* __restrict__ qs,
                                                const float* __restrict__ qn,
                                                const float* __restrict__ vg,
                                                const float* __restrict__ log_sf,
                                                float* __restrict__ meanbuf,
                                                float* __restrict__ klbuf) {
  extern __shared__ float lds[];
  float* qrT = lds;             // [d][l] row tile
  float* qcT = lds + 4352;      // [d][l'] col tile
  float* sT = lds + 2 * 4352;   // [l'][l] scores
  float* vgN = lds + 3 * 4352;  // [l'][d]
  __shared__ float qn_r[64], qn_c[64], redp[256];
  const int lt = blockIdx.x, bh = blockIdx.y;
  const int b = bh >> 3, h = bh & 7;
  const int l0 = lt * 64;
  const int t = threadIdx.x;
  const int tr = (t >> 4) * 4, tn = (t & 15) * 4;
  load_tile_t(qrT, qs + ((size_t)bh * 512 + l0) * 64, 64);
  if (t < 64) qn_r[t] = qn[bh * 512 + l0 + t];
  const float lsf = log_sf[h];
  float acc[4][4] = {};
  for (int c0 = 0; c0 < 512; c0 += 64) {
    __syncthreads();
    load_tile_t(qcT, qs + ((size_t)bh * 512 + c0) * 64, 64);
    load_tile_n(vgN, vg + ((size_t)bh * 512 + c0) * 64, 64);
    if (t < 64) qn_c[t] = qn[bh * 512 + c0 + t];
    __syncthreads();
    float dt[4][4] = {};
    mma64(qrT, qcT, tr, tn, dt);
    float arow[4], acol[4];
#pragma unroll
    for (int i = 0; i < 4; ++i) arow[i] = -0.5f * qn_r[tr + i];
#pragma unroll
    for (int j = 0; j < 4; ++j) acol[j] = -0.5f * qn_c[tn + j] + lsf;
#pragma unroll
    for (int i = 0; i < 4; ++i)
#pragma unroll
      for (int j = 0; j < 4; ++j)
        sT[(tn + j) * 68 + (tr + i)] = __expf(dt[i][j] + arow[i] + acol[j]);
    __syncthreads();
    mma64(sT, vgN, tr, tn, acc);  // += scores @ vg
  }
  float pb = 0.f;
#pragma unroll
  for (int i = 0; i < 4; ++i) {
    size_t rowbase = ((size_t)bh * 512 + l0 + tr + i) * 64 + tn;
    float4 vgr = *(const float4*)(vg + rowbase);
    float4 mb = *(const float4*)(meanbuf + rowbase);
    pb += acc[i][0] * vgr.x + acc[i][1] * vgr.y + acc[i][2] * vgr.z + acc[i][3] * vgr.w;
    mb.x += acc[i][0]; mb.y += acc[i][1]; mb.z += acc[i][2]; mb.w += acc[i][3];
    *(float4*)(meanbuf + rowbase) = mb;
  }
  redp[t] = pb;
  __syncthreads();
  if (t < 64) {
    float s = redp[t] + redp[t + 64] + redp[t + 128] + redp[t + 192];
#pragma unroll
    for (int off = 32; off > 0; off >>= 1) s += __shfl_down(s, off);
    if (t == 0) atomicAdd(&klbuf[3 + b], s);
  }
}

// ---------- k10: v3sq[b,h,d,l] = || v1_l^T S_hd ||^2 (triangular skip) ----
// S_hd is lower-triangular: S[k][n]==0 for k<n. Lanes are remapped so the
// output-column group tn=(t>>4)*4 is wave-quantized (wave w covers columns
// 16w..16w+15); the k-loop then starts at the wave-uniform kstart=16w with
// zero error (skipped terms hit the exact-zero upper triangle). Wave trip
// counts {64,48,32,16} -> 62.5% of the dense FMA issue, no divergence.
__global__ __launch_bounds__(256) void k10_v3sq(const float* __restrict__ v1,
                                                const float* __restrict__ sbuf,
                                                float* __restrict__ v3) {
  __shared__ float v1T[64 * 68];  // [m][l]
  __shared__ float sN[64 * 68];   // [m][n]
  __shared__ float red[64 * 17];
  const int x = blockIdx.x;  // bh*64 + d
  const int lt = blockIdx.y;
  const int bh = x >> 6;
  const int hd = (bh & 7) * 64 + (x & 63);
  const int t = threadIdx.x;
  const int tr = (t & 15) * 4;        // row group (l)
  const int tn = (t >> 4) * 4;        // col group (n), wave-quantized
  const int kstart = (t >> 6) << 4;   // wave-uniform 16*wave_id <= tn
  load_tile_t(v1T, v1 + ((size_t)bh * 512 + lt * 64) * 64, 64);
  load_tile_n(sN, sbuf + (size_t)hd * 4096, 64);
  __syncthreads();
  float acc[4][4] = {};
  for (int k0 = kstart; k0 < 64; k0 += 16) {
#pragma unroll
    for (int kk = 0; kk < 16; ++kk) {
      const int k = k0 + kk;
      float4 av = *(const float4*)(v1T + k * 68 + tr);
      float4 bv = *(const float4*)(sN + k * 68 + tn);
      float a[4] = {av.x, av.y, av.z, av.w};
      float b[4] = {bv.x, bv.y, bv.z, bv.w};
#pragma unroll
      for (int i = 0; i < 4; ++i)
#pragma unroll
        for (int j = 0; j < 4; ++j) acc[i][j] = fmaf(a[i], b[j], acc[i][j]);
    }
  }
#pragma unroll
  for (int i = 0; i < 4; ++i)
    red[(tr + i) * 17 + (t >> 4)] =
        acc[i][0] * acc[i][0] + acc[i][1] * acc[i][1] + acc[i][2] * acc[i][2] +
        acc[i][3] * acc[i][3];
  __syncthreads();
  if (t < 64) {
    float s = 0.f;
#pragma unroll
    for (int g = 0; g < 16; ++g) s += red[t * 17 + g];
    v3[(size_t)x * 512 + lt * 64 + t] = s;
  }
}

// ---------- k8: mean2 subtract, chol_covar, samples ----------
__global__ __launch_bounds__(256) void k8_samples(
    const float* __restrict__ v1, const float* __restrict__ v2,
    const float* __restrict__ meanbuf, const float* __restrict__ v3,
    const float* __restrict__ v1sq, const float* __restrict__ eps,
    const float* __restrict__ log_sf, float* __restrict__ smp) {
  extern __shared__ float lds[];
  float* v1T = lds;             // [m][l]
  float* v2N = lds + 4352;      // [m][d]
  float* v3T = lds + 2 * 4352;  // [d][l]
  __shared__ float v1sq_s[64];
  const int lt = blockIdx.x, bh = blockIdx.y;
  const int b = bh >> 3, h = bh & 7;
  const int l0 = lt * 64;
  const int t = threadIdx.x;
  const int tr = (t >> 4) * 4, tn = (t & 15) * 4;
  load_tile_t(v1T, v1 + ((size_t)bh * 512 + l0) * 64, 64);
  load_tile_n(v2N, v2 + (size_t)bh * 4096, 64);
  load_tile_n(v3T, v3 + (size_t)bh * 64 * 512 + l0, 512);
  if (t < 64) v1sq_s[t] = v1sq[bh * 512 + l0 + t];
  __syncthreads();
  float acc[4][4] = {};
  mma64(v1T, v2N, tr, tn, acc);  // mean2[l][d]
  const float sf = __expf(log_sf[h]);
#pragma unroll
  for (int i = 0; i < 4; ++i) {
    const int l = l0 + tr + i;
    size_t mbase = ((size_t)bh * 512 + l) * 64 + tn;
    float4 mb = *(const float4*)(meanbuf + mbase);
    float mean[4] = {mb.x - acc[i][0], mb.y - acc[i][1], mb.z - acc[i][2], mb.w - acc[i][3]};
    float cc[4];
#pragma unroll
    for (int j = 0; j < 4; ++j) {
      float var = sf + v3T[(tn + j) * 68 + (tr + i)] - v1sq_s[tr + i];
      cc[j] = sqrtf(var);
    }
#pragma unroll
    for (int s2 = 0; s2 < 2; ++s2) {
      float4 ep = *(const float4*)(eps + (((size_t)bh * 2 + s2) * 512 + l) * 64 + tn);
      float4 o;
      o.x = mean[0] + cc[0] * ep.x;
      o.y = mean[1] + cc[1] * ep.y;
      o.z = mean[2] + cc[2] * ep.z;
      o.w = mean[3] + cc[3] * ep.w;
      *(float4*)(smp + (((size_t)(b * 2 + s2) * 512 + l) * 512) + h * 64 + tn) = o;
    }
  }
}

// ---------- kfin: KL scalar ----------
__global__ void kfin(const float* __restrict__ klbuf, float* __restrict__ dout) {
  if (threadIdx.x == 0 && blockIdx.x == 0) {
    double pb = 0.0;
    for (int b = 0; b < 8; ++b) pb += (double)klbuf[3 + b] - (double)klbuf[11 + b];
    double kl = -16384.0 + (double)klbuf[0] + (double)klbuf[1] - (double)klbuf[2] + pb / 16.0;
    dout[4194304] = (float)kl;
  }
}

extern "C" void kernel_launch(void* const* d_in, const int* in_sizes, int n_in,
                              void* d_out, int out_size, void* d_ws, size_t ws_size,
                              hipStream_t stream) {
  (void)in_sizes; (void)n_in; (void)out_size; (void)ws_size;
  const float* x     = (const float*)d_in[0];
  const float* cur_k = (const float*)d_in[1];
  const float* eps   = (const float*)d_in[2];
  const float* W_qkv = (const float*)d_in[3];
  const float* lsf   = (const float*)d_in[4];
  const float* lls   = (const float*)d_in[5];
  const float* vind  = (const float*)d_in[6];
  const float* ltri  = (const float*)d_in[7];
  const float* ldia  = (const float*)d_in[8];
  const float* Wo    = (const float*)d_in[9];
  const float* Wob   = (const float*)d_in[10];
  float* out = (float*)d_out;
  float* ws = (float*)d_ws;
  float* qs   = ws + OFF_QS;
  float* vg   = ws + OFF_VG;
  float* qn   = ws + OFF_QN;
  float* kbs  = ws + OFF_KBS;
  float* kbn  = ws + OFF_KBN;
  float* linv = ws + OFF_LINV;
  float* v1   = ws + OFF_V1;
  float* v1s  = ws + OFF_V1SQ;
  float* mean = ws + OFF_MEAN;
  float* v2   = ws + OFF_V2;
  float* sb   = ws + OFF_SBUF;
  float* v3   = ws + OFF_V3;
  float* smp  = ws + OFF_SMP;
  float* kl   = ws + OFF_KL;

  hipMemsetAsync(kl, 0, 32 * sizeof(float), stream);
  gemm_nt_kernel<0><<<dim3(64, 16), 256, 0, stream>>>(x, W_qkv, 512, qs, vg, lls, qn);
  k2_kbeta<<<512, 256, 0, stream>>>(W_qkv, cur_k, lls, kbs, kbn);
  k3_chol<<<8, 64, 0, stream>>>(kbs, kbn, vind, lsf, linv, kl);
  ks_build<<<512, 256, 0, stream>>>(ltri, ldia, sb, kl);
  k4_fused<<<dim3(8, 64), 256, 73984, stream>>>(qs, qn, kbs, kbn, linv, vind, lsf, v1, v1s, mean);
  k5_v2<<<64, 256, 0, stream>>>(v1, vg, v2, kl);
  k6_mean1<<<dim3(8, 64), 256, 69632, stream>>>(qs, qn, vg, lsf, mean, kl);
  k10_v3sq<<<dim3(4096, 8), 256, 0, stream>>>(v1, sb, v3);
  k8_samples<<<dim3(8, 64), 256, 52224, stream>>>(v1, v2, mean, v3, v1s, eps, lsf, smp);
  gemm_nt_kernel<1><<<dim3(128, 8), 256, 0, stream>>>(smp, Wo, 512, out, nullptr, Wob, nullptr);
  kfin<<<1, 64, 0, stream>>>(kl, out);
}